// Round 10
// baseline (574.411 us; speedup 1.0000x reference)
//
#include <hip/hip_runtime.h>
#include <hip/hip_bf16.h>

#define NB   8
#define CCH  256
#define KCH  128
#define SSP  4096

typedef unsigned short u16;
typedef __attribute__((ext_vector_type(8))) short  bfrag;  // 8 bf16 = 4 VGPRs
typedef __attribute__((ext_vector_type(4))) float  ffrag;  // 4 fp32 acc

#define MFMA16(a, b, c) __builtin_amdgcn_mfma_f32_16x16x32_bf16((a), (b), (c), 0, 0, 0)
// u16-index XOR swizzle: flips bits 3-5 (16B granule) by row&7 -> bank spread
#define SWZ(i, r) ((unsigned)(i) ^ ((((unsigned)(r)) & 7u) << 3))

__device__ __forceinline__ u16 f2b(float f) {            // fp32 -> bf16 RNE
    union { float f; unsigned u; } v; v.f = f;
    return (u16)((v.u + 0x7fffu + ((v.u >> 16) & 1u)) >> 16);
}

// ---------------------------------------------------------------------------
// K1: g and phi projections. (unchanged from round 9: double-buffered LDS,
// one lgkmcnt-only barrier per chunk, loads 2 chunks ahead.)
// ---------------------------------------------------------------------------
__global__ __launch_bounds__(256, 2) void proj_gp_kernel(
    const float* __restrict__ x,
    const float* __restrict__ Wg, const float* __restrict__ bg,
    const float* __restrict__ Wp, const float* __restrict__ bp,
    u16* __restrict__ G,   // [N,K,S] transposed
    u16* __restrict__ P)   // [N,S,K]
{
    __shared__ __align__(16) u16 sm[25600];     // 2 x 12800 (xs|wgs|wps)
    const int tid  = threadIdx.x;
    const int wv   = tid >> 6;
    const int lane = tid & 63;
    const int quad = lane >> 4, l16 = lane & 15;
    const int bid  = blockIdx.x;
    const int n  = bid & 7;
    const int s0 = (bid >> 3) * 64;

    const ffrag zf = {0.f, 0.f, 0.f, 0.f};
    ffrag ga[8], pa[8];
#pragma unroll
    for (int kb = 0; kb < 8; kb++) { ga[kb] = zf; pa[kb] = zf; }

    float4 xreg[2], wgreg[4], wpreg[4];

#define K1_LOAD(C0)                                                          \
    {                                                                        \
        _Pragma("unroll")                                                    \
        for (int i = 0; i < 2; i++) {                                        \
            int f = tid + i * 256;                                           \
            int c = f >> 4, s4 = (f & 15) * 4;                               \
            xreg[i] = *(const float4*)&x[((size_t)n * CCH + (C0) + c) * SSP + s0 + s4]; \
        }                                                                    \
        _Pragma("unroll")                                                    \
        for (int i = 0; i < 4; i++) {                                        \
            int f = tid + i * 256;                                           \
            int k = f >> 3, co = (f & 7) * 4;                                \
            wgreg[i] = *(const float4*)&Wg[k * CCH + (C0) + co];             \
            wpreg[i] = *(const float4*)&Wp[k * CCH + (C0) + co];             \
        }                                                                    \
    }

#define K1_COMMIT(B)                                                         \
    {                                                                        \
        const int bb = (B) * 12800;                                          \
        _Pragma("unroll")                                                    \
        for (int i = 0; i < 2; i++) {                                        \
            int f = tid + i * 256;                                           \
            int c = f >> 4, s4 = (f & 15) * 4;                               \
            sm[bb + (s4 + 0) * 40 + c] = f2b(xreg[i].x);                     \
            sm[bb + (s4 + 1) * 40 + c] = f2b(xreg[i].y);                     \
            sm[bb + (s4 + 2) * 40 + c] = f2b(xreg[i].z);                     \
            sm[bb + (s4 + 3) * 40 + c] = f2b(xreg[i].w);                     \
        }                                                                    \
        _Pragma("unroll")                                                    \
        for (int i = 0; i < 4; i++) {                                        \
            int f = tid + i * 256;                                           \
            int k = f >> 3, co = (f & 7) * 4;                                \
            ushort4 g4 = {f2b(wgreg[i].x), f2b(wgreg[i].y), f2b(wgreg[i].z), f2b(wgreg[i].w)}; \
            ushort4 p4 = {f2b(wpreg[i].x), f2b(wpreg[i].y), f2b(wpreg[i].z), f2b(wpreg[i].w)}; \
            *(ushort4*)&sm[bb + 2560 + k * 40 + co] = g4;                    \
            *(ushort4*)&sm[bb + 7680 + k * 40 + co] = p4;                    \
        }                                                                    \
    }

    // prologue: chunk0 -> buf0; chunk1 loads in flight
    K1_LOAD(0)
    K1_COMMIT(0)
    K1_LOAD(32)
    asm volatile("s_waitcnt lgkmcnt(0)" ::: "memory");
    __builtin_amdgcn_s_barrier();

#pragma unroll
    for (int it = 0; it < 8; ++it) {
        if (it < 7) K1_COMMIT((it + 1) & 1)         // chunk it+1 -> idle buf
        if (it < 6) K1_LOAD((it + 2) * 32)          // fly across the barrier
        const int bb = (it & 1) * 12800;
        bfrag a = *(const bfrag*)&sm[bb + (16 * wv + l16) * 40 + quad * 8];
#pragma unroll
        for (int kb = 0; kb < 8; kb++) {
            bfrag bgf = *(const bfrag*)&sm[bb + 2560 + (16 * kb + l16) * 40 + quad * 8];
            bfrag bpf = *(const bfrag*)&sm[bb + 7680 + (16 * kb + l16) * 40 + quad * 8];
            ga[kb] = MFMA16(a, bgf, ga[kb]);
            pa[kb] = MFMA16(a, bpf, pa[kb]);
        }
        asm volatile("s_waitcnt lgkmcnt(0)" ::: "memory");
        __builtin_amdgcn_s_barrier();
    }
#undef K1_LOAD
#undef K1_COMMIT

#pragma unroll
    for (int kb = 0; kb < 8; kb++) {
        int k = l16 + 16 * kb;
        float bgv = bg[k], bpv = bp[k];
        int srow = s0 + 16 * wv + quad * 4;
        ushort4 g4 = {f2b(ga[kb][0] + bgv), f2b(ga[kb][1] + bgv),
                      f2b(ga[kb][2] + bgv), f2b(ga[kb][3] + bgv)};
        *(ushort4*)&G[(size_t)n * KCH * SSP + (size_t)k * SSP + srow] = g4;
#pragma unroll
        for (int r = 0; r < 4; r++)
            P[((size_t)n * SSP + srow + r) * KCH + k] = f2b(pa[kb][r] + bpv);
    }
}

// ---------------------------------------------------------------------------
// K2: fused theta-proj + flash attention + out-proj, all MFMA.
// Round-15 vs round 9 (halving LDS reads left dur flat at 131us -> limiter
// is the per-iter lock-step barrier+vmcnt(0) drain, not any pipe):
//   BARRIER-FREE t-loop. Both MFMA B-fragments are 16 contiguous bytes/lane
//   in the existing global layouts, so they load DIRECTLY global->VGPR:
//     K-frag  = Pb[(t0+16tb+l16)*128 + kc*32 + quad*8]   (QK B-operand)
//     G-frag  = Gt[(16kb+l16)*4096 + t0 + tc*32 + quad*8] (PV B-operand)
//   q split 4 ways (wave = 16 q-rows x all t): K/G frags, PS (wave-private
//   LDS round-trip), O, l are all wave-local -> NO barriers, NO DMA, NO
//   KS/GT staging in the loop; per-wave compiler vmcnt only. All 8 waves
//   on a CU (both co-resident blocks share n!) read identical K/G
//   addresses -> L1 serves repeats. Waves self-stagger for latency hiding.
// LDS map (u16 idx, 16384 = 32 KB):
//   [0,8192)     QS (ph0/qf) / YS (epilogue)    [same rows per wave]
//   [8192,16384) XT@8192+WT@10752 (ph0) / PS wv*1024 (t-loop) / WO (epi)
// ---------------------------------------------------------------------------
__global__ __launch_bounds__(256, 2) void attn_fused_kernel(
    const float* __restrict__ x,
    const float* __restrict__ Wt, const float* __restrict__ bt,
    const u16* __restrict__ Pb,   // phi rows bf16 [N,S,K]
    const u16* __restrict__ Gt,   // g bf16 TRANSPOSED [N,K,S]
    const float* __restrict__ Wo, const float* __restrict__ bo,
    float* __restrict__ out)
{
    __shared__ __align__(16) u16 sm[16384];     // 32 KB
    const int tid  = threadIdx.x;
    const int wv   = tid >> 6;                  // 0..3
    const int lane = tid & 63;
    const int quad = lane >> 4, l16 = lane & 15;
    const int bid  = blockIdx.x;
    const int n    = bid & 7;
    const int q0   = (bid >> 3) * 64;
    // 1/sqrt(128) * log2(e): exp(s*scale) == exp2(s*qscale)
    const float qscale = 0.08838834764831845f * 1.4426950408889634f;
    const ffrag zf = {0.f, 0.f, 0.f, 0.f};

    const int QSb = 0, XTb = 8192, WTb = 10752;
    const int PSw = 8192 + wv * 1024;           // per-wave PS [16 q][64 t]
    const int YSb = 0, WOb = 8192;

    const u16* Pbase = Pb + (size_t)n * SSP * KCH;
    const u16* Gbase = Gt + (size_t)n * KCH * SSP;

    // ---------------- Phase 0: Qs = (theta(x)+bt)*qscale, bf16 ----------------
    {
        ffrag qa[8];
#pragma unroll
        for (int kb = 0; kb < 8; kb++) qa[kb] = zf;

        for (int c0 = 0; c0 < CCH; c0 += 32) {
#pragma unroll
            for (int i = 0; i < 2; i++) {
                int f = tid + i * 256;
                int c = f >> 4, s4 = (f & 15) * 4;
                float4 xv = *(const float4*)&x[((size_t)n * CCH + c0 + c) * SSP + q0 + s4];
                sm[XTb + (s4 + 0) * 40 + c] = f2b(xv.x);
                sm[XTb + (s4 + 1) * 40 + c] = f2b(xv.y);
                sm[XTb + (s4 + 2) * 40 + c] = f2b(xv.z);
                sm[XTb + (s4 + 3) * 40 + c] = f2b(xv.w);
            }
#pragma unroll
            for (int i = 0; i < 4; i++) {
                int f = tid + i * 256;
                int k = f >> 3, co = (f & 7) * 4;
                float4 wq4 = *(const float4*)&Wt[k * CCH + c0 + co];
                ushort4 q4 = {f2b(wq4.x), f2b(wq4.y), f2b(wq4.z), f2b(wq4.w)};
                *(ushort4*)&sm[WTb + k * 40 + co] = q4;
            }
            __syncthreads();
            bfrag aq = *(const bfrag*)&sm[XTb + (16 * wv + l16) * 40 + quad * 8];
#pragma unroll
            for (int kb = 0; kb < 8; kb++) {
                bfrag bw = *(const bfrag*)&sm[WTb + (16 * kb + l16) * 40 + quad * 8];
                qa[kb] = MFMA16(aq, bw, qa[kb]);
            }
            __syncthreads();
        }
        // QS write: own rows (16wv..16wv+15) — in-wave only from here on.
#pragma unroll
        for (int kb = 0; kb < 8; kb++) {
            float btv = bt[l16 + 16 * kb];
#pragma unroll
            for (int r = 0; r < 4; r++) {
                int row = 16 * wv + quad * 4 + r;
                sm[QSb + SWZ(row * 128 + l16 + 16 * kb, row)] = f2b((qa[kb][r] + btv) * qscale);
            }
        }
    }

    // ---- hoist Q A-fragments (own rows; in-wave LDS ordering suffices) ----
    bfrag qf[4];
#pragma unroll
    for (int kc = 0; kc < 4; kc++)
        qf[kc] = *(const bfrag*)&sm[QSb + SWZ((16 * wv + l16) * 128 + kc * 32 + quad * 8, l16)];

    // ---------------- Phase 1: flash attention, BARRIER-FREE ----------------
    ffrag O[8];
#pragma unroll
    for (int kb = 0; kb < 8; kb++) O[kb] = zf;
    float l_r[4] = {0.f, 0.f, 0.f, 0.f};

    for (int t0 = 0; t0 < SSP; t0 += 64) {
        // ---- K fragments direct global->VGPR (QK B-operand layout) ----
        bfrag kf[16];
#pragma unroll
        for (int tb = 0; tb < 4; tb++)
#pragma unroll
            for (int kc = 0; kc < 4; kc++)
                kf[tb * 4 + kc] = *(const bfrag*)(Pbase
                    + (size_t)(t0 + 16 * tb + l16) * KCH + kc * 32 + quad * 8);

        // ---- QK^T (Q A-frags from registers) ----
        ffrag sa[4];
#pragma unroll
        for (int tb = 0; tb < 4; tb++) sa[tb] = zf;
#pragma unroll
        for (int kc = 0; kc < 4; kc++)
#pragma unroll
            for (int tb = 0; tb < 4; tb++)
                sa[tb] = MFMA16(qf[kc], kf[tb * 4 + kc], sa[tb]);

        // ---- G fragments direct global->VGPR (PV B-operand layout);
        //      issued before softmax so L2 latency hides under it ----
        bfrag gf[16];
#pragma unroll
        for (int kb = 0; kb < 8; kb++)
#pragma unroll
            for (int tc = 0; tc < 2; tc++)
                gf[kb * 2 + tc] = *(const bfrag*)(Gbase
                    + (size_t)(16 * kb + l16) * SSP + t0 + tc * 32 + quad * 8);

        // ---- softmax numerator; l accumulated per-lane ----
#pragma unroll
        for (int r = 0; r < 4; r++) {
            float p0 = __builtin_amdgcn_exp2f(sa[0][r]);
            float p1 = __builtin_amdgcn_exp2f(sa[1][r]);
            float p2 = __builtin_amdgcn_exp2f(sa[2][r]);
            float p3 = __builtin_amdgcn_exp2f(sa[3][r]);
            l_r[r] += (p0 + p1) + (p2 + p3);
            int row = quad * 4 + r;             // q-local 0..15
            int rb = row * 64 + l16;
            sm[PSw + SWZ(rb +  0, row)] = f2b(p0);
            sm[PSw + SWZ(rb + 16, row)] = f2b(p1);
            sm[PSw + SWZ(rb + 32, row)] = f2b(p2);
            sm[PSw + SWZ(rb + 48, row)] = f2b(p3);
        }
        // PS is wave-private: in-wave LDS ordering, no barrier.

        // ---- PV: O += P * G ----
#pragma unroll
        for (int tc = 0; tc < 2; tc++) {
            bfrag ap = *(const bfrag*)&sm[PSw + SWZ(l16 * 64 + tc * 32 + quad * 8, l16)];
#pragma unroll
            for (int kb = 0; kb < 8; kb++)
                O[kb] = MFMA16(ap, gf[kb * 2 + tc], O[kb]);
        }
    }

    // ---------------- Phase 2: reduce l; y -> YS; out = x + Wo*y + bo ----
    {
        float rs0 = l_r[0], rs1 = l_r[1], rs2 = l_r[2], rs3 = l_r[3];
#pragma unroll
        for (int m = 1; m <= 8; m <<= 1) {
            rs0 += __shfl_xor(rs0, m);
            rs1 += __shfl_xor(rs1, m);
            rs2 += __shfl_xor(rs2, m);
            rs3 += __shfl_xor(rs3, m);
        }
        float lr0 = 1.0f / rs0, lr1 = 1.0f / rs1, lr2 = 1.0f / rs2, lr3 = 1.0f / rs3;
#pragma unroll
        for (int kb = 0; kb < 8; kb++) {
            int rowb = 16 * wv + quad * 4;
            sm[YSb + SWZ((rowb + 0) * 128 + l16 + 16 * kb, rowb + 0)] = f2b(O[kb][0] * lr0);
            sm[YSb + SWZ((rowb + 1) * 128 + l16 + 16 * kb, rowb + 1)] = f2b(O[kb][1] * lr1);
            sm[YSb + SWZ((rowb + 2) * 128 + l16 + 16 * kb, rowb + 2)] = f2b(O[kb][2] * lr2);
            sm[YSb + SWZ((rowb + 3) * 128 + l16 + 16 * kb, rowb + 3)] = f2b(O[kb][3] * lr3);
        }
    }

#pragma unroll
    for (int qtr = 0; qtr < 4; qtr++) {
        __syncthreads();    // all waves past t-loop (PS dead) / prev WO read
        // stage Wo rows [qtr*64, qtr*64+64) bf16, swizzled [64][128]
#pragma unroll
        for (int i = 0; i < 8; i++) {
            int f = tid + i * 256;
            int c = f >> 5, ko = (f & 31) * 4;
            float4 w = *(const float4*)&Wo[(size_t)(qtr * 64 + c) * KCH + ko];
            ushort4 w4 = {f2b(w.x), f2b(w.y), f2b(w.z), f2b(w.w)};
            *(ushort4*)&sm[WOb + SWZ(c * 128 + ko, c)] = w4;
        }
        __syncthreads();

        ffrag zc[4];
#pragma unroll
        for (int cb = 0; cb < 4; cb++) zc[cb] = zf;
#pragma unroll
        for (int kc = 0; kc < 4; kc++) {
            bfrag ay = *(const bfrag*)&sm[YSb + SWZ((16 * wv + l16) * 128 + kc * 32 + quad * 8, l16)];
#pragma unroll
            for (int cb = 0; cb < 4; cb++) {
                bfrag bw = *(const bfrag*)&sm[WOb + SWZ((16 * cb + l16) * 128 + kc * 32 + quad * 8, l16)];
                zc[cb] = MFMA16(ay, bw, zc[cb]);
            }
        }
#pragma unroll
        for (int cb = 0; cb < 4; cb++) {
            int c = qtr * 64 + 16 * cb + l16;
            float bc = bo[c];
            size_t base = ((size_t)n * CCH + c) * SSP + q0 + 16 * wv + quad * 4;
            float4 xv = *(const float4*)&x[base];
            float4 ov;
            ov.x = xv.x + zc[cb][0] + bc;
            ov.y = xv.y + zc[cb][1] + bc;
            ov.z = xv.z + zc[cb][2] + bc;
            ov.w = xv.w + zc[cb][3] + bc;
            *(float4*)&out[base] = ov;
        }
    }
}

// ---------------------------------------------------------------------------
extern "C" void kernel_launch(void* const* d_in, const int* in_sizes, int n_in,
                              void* d_out, int out_size, void* d_ws, size_t ws_size,
                              hipStream_t stream) {
    const float* x  = (const float*)d_in[0];
    const float* Wg = (const float*)d_in[1];
    const float* bg = (const float*)d_in[2];
    const float* Wt = (const float*)d_in[3];
    const float* bt = (const float*)d_in[4];
    const float* Wp = (const float*)d_in[5];
    const float* bp = (const float*)d_in[6];
    const float* Wo = (const float*)d_in[7];
    const float* bo = (const float*)d_in[8];
    float* out = (float*)d_out;

    // ws: 16 MB total (verified-safe): G^T bf16 8MB + P bf16 8MB.
    u16* G = (u16*)d_ws;                       // [N,K,S] transposed
    u16* P = G + (size_t)NB * SSP * KCH;       // [N,S,K]

    proj_gp_kernel<<<dim3(NB * SSP / 64), 256, 0, stream>>>(x, Wg, bg, Wp, bp, G, P);
    attn_fused_kernel<<<dim3(NB * SSP / 64), 256, 0, stream>>>(x, Wt, bt, P, G, Wo, bo, out);
}